// Round 12
// baseline (201.316 us; speedup 1.0000x reference)
//
#include <hip/hip_runtime.h>
#include <hip/hip_bf16.h>
#include <math.h>

namespace {

constexpr int B = 2;
constexpr int N = 8192;
constexpr int D = 64;
constexpr int GRID = 10;
constexpr int GC = GRID * GRID * GRID;     // 1000 cells per batch
constexpr float H = 0.1f;
constexpr float NEGS = 0.2f;
constexpr float BN_INV = 0.9999950000374997f;   // 1/sqrt(1+1e-5)
constexpr float RSQN = 0.011048543456039806f;   // 1/sqrt(8192)
constexpr int NQUAD = B * N / 4;           // wave-iterations of 4 queries

typedef __attribute__((ext_vector_type(8))) short bf16x8;
typedef __attribute__((ext_vector_type(16))) float f32x16;

union Frag { int4 i4; unsigned u[4]; bf16x8 h; };

__device__ __forceinline__ float lrelu(float v) { return fmaxf(v, NEGS * v); }

__device__ __forceinline__ unsigned pk2(float a, float b) {
  __hip_bfloat162 h2 = __float22bfloat162_rn(make_float2(a, b));
  unsigned r;
  __builtin_memcpy(&r, &h2, 4);
  return r;
}
__device__ __forceinline__ float blo(unsigned u) { return __uint_as_float(u << 16); }
__device__ __forceinline__ float bhi(unsigned u) { return __uint_as_float(u & 0xFFFF0000u); }

__device__ __forceinline__ f32x16 MF(int4 a, const Frag& b, f32x16 c) {
  Frag af; af.i4 = a;
  return __builtin_amdgcn_mfma_f32_32x32x16_bf16(af.h, b.h, c, 0, 0, 0);
}

// 16-lane-row reductions via DPP row_ror (pure VALU, no DS pipe).
template <int CTRL>
__device__ __forceinline__ float dpp_add(float v) {
  int t = __builtin_amdgcn_update_dpp(0, __float_as_int(v), CTRL, 0xF, 0xF, false);
  return v + __int_as_float(t);
}
__device__ __forceinline__ float rsum16(float v) {
  v = dpp_add<0x128>(v);   // row_ror:8
  v = dpp_add<0x124>(v);   // row_ror:4
  v = dpp_add<0x122>(v);   // row_ror:2
  v = dpp_add<0x121>(v);   // row_ror:1
  return v;
}
template <int CTRL>
__device__ __forceinline__ unsigned long long dpp_min_u64(unsigned long long k) {
  int lo = __builtin_amdgcn_update_dpp(0, (int)(unsigned)k, CTRL, 0xF, 0xF, false);
  int hi = __builtin_amdgcn_update_dpp(0, (int)(unsigned)(k >> 32), CTRL, 0xF, 0xF, false);
  unsigned long long o = ((unsigned long long)(unsigned)hi << 32) | (unsigned)lo;
  return o < k ? o : k;
}
__device__ __forceinline__ unsigned long long rmin16_u64(unsigned long long k) {
  k = dpp_min_u64<0x128>(k);
  k = dpp_min_u64<0x124>(k);
  k = dpp_min_u64<0x122>(k);
  k = dpp_min_u64<0x121>(k);
  return k;
}

__device__ __forceinline__ int cellco(float v) {
  int c = (int)(v * 10.0f);
  return min(max(c, 0), GRID - 1);
}

// D-layout f32 (x0: chans 0-31 rows, x1: chans 32-63) -> B-fragments for next layer.
__device__ __forceinline__ void buildB(const f32x16& x0, const f32x16& x1, int h, Frag Bf[4]) {
  unsigned Z[8][2];
  #pragma unroll
  for (int q = 0; q < 4; ++q) {
    Z[q][0]     = pk2(x0[4*q+0], x0[4*q+1]);
    Z[q][1]     = pk2(x0[4*q+2], x0[4*q+3]);
    Z[4+q][0]   = pk2(x1[4*q+0], x1[4*q+1]);
    Z[4+q][1]   = pk2(x1[4*q+2], x1[4*q+3]);
  }
  unsigned S[8][2];
  #pragma unroll
  for (int q = 0; q < 8; ++q) {
    S[q][0] = (unsigned)__shfl_xor((int)Z[q][0], 32);
    S[q][1] = (unsigned)__shfl_xor((int)Z[q][1], 32);
  }
  #pragma unroll
  for (int t = 0; t < 4; ++t) {
    int qq = (t >> 1) * 4 + 2 * (t & 1);
    Bf[t].u[0] = h ? S[qq+1][0] : Z[qq][0];
    Bf[t].u[1] = h ? S[qq+1][1] : Z[qq][1];
    Bf[t].u[2] = h ? Z[qq+1][0] : S[qq][0];
    Bf[t].u[3] = h ? Z[qq+1][1] : S[qq][1];
  }
}

__device__ __forceinline__ f32x16 biasAct(f32x16 d, const float4* bp, int mt, int h) {
  f32x16 r;
  #pragma unroll
  for (int q = 0; q < 4; ++q) {
    float4 bb = bp[h * 8 + mt * 4 + q];
    r[4*q+0] = lrelu(d[4*q+0] + bb.x);
    r[4*q+1] = lrelu(d[4*q+1] + bb.y);
    r[4*q+2] = lrelu(d[4*q+2] + bb.z);
    r[4*q+3] = lrelu(d[4*q+3] + bb.w);
  }
  return r;
}

// ---------------- prep: pack A-fragments (bf16, BN scale folded; Wg2 also folds RSQN) ----------------
struct PrepArgs {
  const float* W[9];       // W1,Wq,Wk,Wv,Wd2,Wg1,Wg2,W2,Wd1
  const float* scale[9];
  const float* bias[5];    // b1,bd2,bg1,bg2,b2
  const float* bd1;
};

__global__ __launch_bounds__(256) void prep_kernel(PrepArgs a, unsigned short* AF, float* biasAll) {
  int mi = blockIdx.x;
  int tid = threadIdx.x;
  if (mi < 8) {
    int off = (mi == 7) ? 29696 : mi * 4096;
    const float* W = a.W[mi];
    const float* G = a.scale[mi];
    unsigned short* dst = AF + off;
    for (int e = tid; e < 4096; e += 256) {
      int i = e & 7, lane = (e >> 3) & 63, t = (e >> 9) & 3, mt = e >> 11;
      int row = 32 * mt + (lane & 31);
      int k = 16 * t + 8 * (lane >> 5) + i;
      float v = W[row * 64 + k];
      if (G) v *= G[row] * BN_INV;
      if (mi == 6) v *= RSQN;                  // fold 1/sqrt(N) into Wg2
      __hip_bfloat16 hb = __float2bfloat16(v);
      __builtin_memcpy(&dst[e], &hb, 2);
    }
  } else {
    const float* W = a.W[8];
    const float* G = a.scale[8];
    for (int e = tid; e < 1024; e += 256) {
      int i = e & 7, lane = (e >> 3) & 63, mt = e >> 9;
      int row = 32 * mt + (lane & 31), h = lane >> 5;
      float v = 0.f;
      if (h == 0) {
        if (i < 3) v = W[row * 3 + i] * G[row] * BN_INV;
        else if (i == 3) v = a.bd1[row];
      }
      __hip_bfloat16 hb = __float2bfloat16(v);
      __builtin_memcpy(&AF[28672 + e], &hb, 2);
    }
    for (int e = tid; e < 320; e += 256) {
      int ai = e >> 6, idx = e & 63;
      int h = idx >> 5, mt = (idx >> 4) & 1, q = (idx >> 2) & 3, j = idx & 3;
      float bv = a.bias[ai][32 * mt + 8 * q + 4 * h + j];
      if (ai == 3) bv *= RSQN;                 // fold 1/sqrt(N) into bg2
      biasAll[e] = bv;
    }
  }
}

// ---------------- pos4 + cell id + histogram ----------------
__global__ __launch_bounds__(256) void pos4cid_kernel(
    const float* __restrict__ pos, float* __restrict__ pos4,
    int* __restrict__ cid16, int* __restrict__ cellCount)
{
  int i = blockIdx.x * 256 + threadIdx.x;
  int b = i >> 13;
  int n = i & (N - 1);
  const float* pb = pos + (size_t)b * 3 * N;
  float x = pb[n], y = pb[N + n], z = pb[2 * N + n];
  float4 v = {x, y, z, x * x + y * y + z * z};
  *reinterpret_cast<float4*>(pos4 + (size_t)i * 4) = v;
  int cid = (cellco(z) * GRID + cellco(y)) * GRID + cellco(x);
  cid16[i] = cid;
  atomicAdd(&cellCount[b * GC + cid], 1);
}

// ---------------- scan: exclusive prefix over 2048 cell counts (single block) ----------------
__global__ __launch_bounds__(1024) void scan_kernel(
    const int* __restrict__ cnt, int* __restrict__ cellStart)
{
  __shared__ int s[2][2048];
  int t = threadIdx.x;
  s[0][t] = cnt[t];
  s[0][t + 1024] = cnt[t + 1024];
  __syncthreads();
  int src = 0;
  for (int off = 1; off < 2048; off <<= 1) {
    int dst = src ^ 1;
    for (int i = t; i < 2048; i += 1024) {
      int v = s[src][i];
      if (i >= off) v += s[src][i - off];
      s[dst][i] = v;
    }
    __syncthreads();
    src ^= 1;
  }
  cellStart[t] = (t == 0) ? 0 : s[src][t - 1];
  cellStart[t + 1024] = s[src][t + 1023];
}

// ---------------- scatter: counting-sort points by cell (+ inverse map orig->sorted) ----------------
__global__ __launch_bounds__(256) void scatter_kernel(
    const float* __restrict__ pos4, const int* __restrict__ cid16,
    const int* __restrict__ cellStart, int* __restrict__ cellOfs,
    float4* __restrict__ pos4s, int* __restrict__ sid, int* __restrict__ inv)
{
  int i = blockIdx.x * 256 + threadIdx.x;
  int b = i >> 13;
  int cg = b * GC + cid16[i];
  int dst = cellStart[cg] + atomicAdd(&cellOfs[cg], 1);
  pos4s[dst] = *reinterpret_cast<const float4*>(pos4 + (size_t)i * 4);
  sid[dst] = i & (N - 1);
  inv[i] = dst;                                // global sorted slot of orig point
}

// ---------------- knn: 16-lane group per query; atomic work dispenser for load balance ----------------
__global__ __launch_bounds__(256) void knn_shell_kernel(
    const float4* __restrict__ pos4s, const int* __restrict__ sid,
    const int* __restrict__ cellStart, int* __restrict__ knn_s,
    int* __restrict__ workCtr)
{
  constexpr unsigned long long SENT = ~0ULL;
  int lq = threadIdx.x & 15;                          // lane within group
  int wl = (threadIdx.x & 63) >> 4;                   // group (query) within wave

  #pragma unroll 1
  for (;;) {
    int quad;
    if ((threadIdx.x & 63) == 0) quad = atomicAdd(workCtr, 1);
    quad = __shfl(quad, 0);                           // wave-uniform
    if (quad >= NQUAD) break;

    int wid = quad * 4 + wl;                          // global sorted slot = query
    int b = wid >> 13;
    float4 q = pos4s[wid];
    int cx = cellco(q.x), cy = cellco(q.y), cz = cellco(q.z);
    const int cbase = b * GC;
    int myout = 0;

    bool done = false;
    #pragma unroll 1
    for (int r = 1; r < GRID; ++r) {
      if (!done) {
        unsigned long long dk[16];
        #pragma unroll
        for (int j = 0; j < 16; ++j) dk[j] = SENT;

        int x0 = max(cx - r, 0), x1 = min(cx + r, GRID - 1);
        int y0 = max(cy - r, 0), y1 = min(cy + r, GRID - 1);
        int z0 = max(cz - r, 0), z1 = min(cz + r, GRID - 1);
        #pragma unroll 1
        for (int zz = z0; zz <= z1; ++zz) {
          #pragma unroll 1
          for (int yy = y0; yy <= y1; ++yy) {
            int rowc = cbase + (zz * GRID + yy) * GRID;
            int i0 = cellStart[rowc + x0], i1 = cellStart[rowc + x1 + 1];
            #pragma unroll 1
            for (int i = i0 + lq; i < i1; i += 16) {
              float4 cp = pos4s[i];
              float inn = q.x * cp.x + q.y * cp.y + q.z * cp.z;
              float dist = fmaxf(fmaf(-2.f, inn, q.w + cp.w), 0.f);
              unsigned long long key =
                  ((unsigned long long)__float_as_uint(dist) << 26) |
                  ((unsigned long long)(unsigned)sid[i] << 13) |
                  (unsigned long long)(unsigned)(i & (N - 1));
              if (key < dk[15]) {
                bool bj = true;
                #pragma unroll
                for (int j = 15; j >= 1; --j) {
                  bool bjm1 = key < dk[j - 1];
                  dk[j] = bj ? (bjm1 ? dk[j - 1] : key) : dk[j];
                  bj = bjm1;
                }
                if (bj) dk[0] = key;
              }
            }
          }
        }

        // extract group top-16 via DPP u64 min; round-e winner kept by lane e
        float dlast = 0.f;
        #pragma unroll 1
        for (int e = 0; e < 16; ++e) {
          unsigned long long m = rmin16_u64(dk[0]);
          if (dk[0] == m) {                      // unique winner (keys embed unique ids)
            #pragma unroll
            for (int j = 0; j < 15; ++j) dk[j] = dk[j + 1];
            dk[15] = SENT;
          }
          if (lq == e) myout = (int)(m & 0x1FFFULL);
          dlast = __uint_as_float((unsigned)(m >> 26));
        }

        // margin certificate from searched window (domain faces -> inf)
        float mg = 3.4e38f;
        if (cx - r > 0)        mg = fminf(mg, q.x - (cx - r) * H);
        if (cx + r < GRID - 1) mg = fminf(mg, (cx + r + 1) * H - q.x);
        if (cy - r > 0)        mg = fminf(mg, q.y - (cy - r) * H);
        if (cy + r < GRID - 1) mg = fminf(mg, (cy + r + 1) * H - q.y);
        if (cz - r > 0)        mg = fminf(mg, q.z - (cz - r) * H);
        if (cz + r < GRID - 1) mg = fminf(mg, (cz + r + 1) * H - q.z);
        done = (dlast <= mg * mg * 0.999f);      // group-uniform
      }
      if (__all(done)) break;
    }

    knn_s[(size_t)wid * 16 + lq] = myout;        // one coalesced store per group
  }
}

// ---------------- qkv (MFMA): blockIdx.y selects output matrix; outputs at SORTED slots ----------------
__global__ __launch_bounds__(256) void qkv_kernel(
    const float* __restrict__ feats, const int4* __restrict__ AF,
    const float* __restrict__ b1p, const int* __restrict__ inv,
    uint2* __restrict__ qT, uint2* __restrict__ kT, uint2* __restrict__ vT)
{
  __shared__ int4 sA[1024];   // W1 | W{q,k,v}[blockIdx.y]
  int my = blockIdx.y;
  for (int i = threadIdx.x; i < 512; i += 256) {
    sA[i] = AF[i];
    sA[512 + i] = AF[512 * (1 + my) + i];
  }
  __syncthreads();
  int lane = threadIdx.x & 63, w = threadIdx.x >> 6;
  int gw = blockIdx.x * 4 + w;
  int col = lane & 31, h = lane >> 5;
  int nb = gw * 32;
  int b = nb >> 13;
  int n = (nb & (N - 1)) + col;
  size_t gpt = (size_t)b * N + n;
  int sv = inv[gpt];                            // sorted slot (coalesced read)
  const float* fb = feats + (size_t)b * D * N + n;

  Frag Bf[4];
  #pragma unroll
  for (int t = 0; t < 4; ++t) {
    int c0 = 16 * t + 8 * h;
    float f[8];
    #pragma unroll
    for (int i = 0; i < 8; ++i) f[i] = fb[(size_t)(c0 + i) * N];
    #pragma unroll
    for (int d_ = 0; d_ < 4; ++d_) Bf[t].u[d_] = pk2(f[2*d_], f[2*d_+1]);
  }
  f32x16 acc0 = {}, acc1 = {};
  #pragma unroll
  for (int t = 0; t < 4; ++t) {
    acc0 = MF(sA[t * 64 + lane], Bf[t], acc0);
    acc1 = MF(sA[(4 + t) * 64 + lane], Bf[t], acc1);
  }
  const float4* bp = (const float4*)b1p;
  f32x16 x0 = biasAct(acc0, bp, 0, h);
  f32x16 x1 = biasAct(acc1, bp, 1, h);
  Frag Bx[4];
  buildB(x0, x1, h, Bx);

  uint2* op = (my == 0) ? qT : (my == 1) ? kT : vT;
  f32x16 a0 = {}, a1 = {};
  #pragma unroll
  for (int t = 0; t < 4; ++t) {
    a0 = MF(sA[512 + t * 64 + lane], Bx[t], a0);
    a1 = MF(sA[512 + (4 + t) * 64 + lane], Bx[t], a1);
  }
  #pragma unroll
  for (int q = 0; q < 4; ++q) {
    uint2 v0, v1;
    v0.x = pk2(a0[4*q+0], a0[4*q+1]); v0.y = pk2(a0[4*q+2], a0[4*q+3]);
    v1.x = pk2(a1[4*q+0], a1[4*q+1]); v1.y = pk2(a1[4*q+2], a1[4*q+3]);
    op[(size_t)sv * 16 + 2 * q + h] = v0;       // scatter write to sorted slot
    op[(size_t)sv * 16 + 8 + 2 * q + h] = v1;
  }
}

// ---------------- fused (MFMA): LDS weights; inline sorted-space gathers; DPP softmax ----------------
__global__ __launch_bounds__(256) void fused_kernel(
    const float4* __restrict__ pos4s, const int* __restrict__ sid,
    const int* __restrict__ knn_s,
    const uint2* __restrict__ qT, const uint2* __restrict__ kT, const uint2* __restrict__ vT,
    const int4* __restrict__ AF,      // [Wd2 | Wg1 | Wg2 | Wd1]
    const float* __restrict__ biases, // bd2p | bg1p | bg2p(RSQN-folded)
    uint2* __restrict__ res_ws)       // bf16-packed res, orig order, B-frag pair layout
{
  int lane = threadIdx.x & 63, w = threadIdx.x >> 6;
  int gw = blockIdx.x * 4 + w;
  int col = lane & 31, h = lane >> 5;
  int p = col >> 4, kk = col & 15;
  int sbase = gw * 2;
  int b = sbase >> 13;
  int s = sbase + p;                            // global sorted slot of own point

  // point-level loads issued before LDS stage (hide under stage+barrier)
  int m_loc = knn_s[(size_t)s * 16 + kk];       // sorted-local neighbor idx (coalesced)
  int orig = sid[s];
  float4 P = pos4s[s];

  __shared__ int4 sA[1664];
  for (int i = threadIdx.x; i < 1664; i += 256) sA[i] = AF[i];
  __syncthreads();
  const float4* bpd2 = (const float4*)(biases);
  const float4* bpg1 = (const float4*)(biases + 64);
  const float4* bpg2 = (const float4*)(biases + 128);

  size_t ms = (size_t)b * N + m_loc;            // global sorted neighbor slot
  float4 Q = pos4s[ms];
  float rx = P.x - Q.x, ry = P.y - Q.y, rz = P.z - Q.z;

  // L0: pe = lrelu(s*Wd1@rel + bd1)   (bias via B k=3 column)
  Frag B0;
  B0.u[0] = h ? 0u : pk2(rx, ry);
  B0.u[1] = h ? 0u : pk2(rz, 1.0f);
  B0.u[2] = 0u; B0.u[3] = 0u;
  f32x16 acc0 = {}, acc1 = {};
  acc0 = MF(sA[1536 + lane], B0, acc0);
  acc1 = MF(sA[1600 + lane], B0, acc1);
  f32x16 pe0, pe1;
  #pragma unroll
  for (int i = 0; i < 16; ++i) { pe0[i] = lrelu(acc0[i]); pe1[i] = lrelu(acc1[i]); }
  Frag Bp[4];
  buildB(pe0, pe1, h, Bp);

  // L1: pos_enc = lrelu(s*Wd2@pe + bd2)
  acc0 = (f32x16){}; acc1 = (f32x16){};
  #pragma unroll
  for (int t = 0; t < 4; ++t) {
    acc0 = MF(sA[t * 64 + lane], Bp[t], acc0);
    acc1 = MF(sA[(4 + t) * 64 + lane], Bp[t], acc1);
  }
  f32x16 pn0 = biasAct(acc0, bpd2, 0, h);
  f32x16 pn1 = biasAct(acc1, bpd2, 1, h);

  unsigned pep[8][2];
  #pragma unroll
  for (int q = 0; q < 4; ++q) {
    pep[q][0]   = pk2(pn0[4*q+0], pn0[4*q+1]);
    pep[q][1]   = pk2(pn0[4*q+2], pn0[4*q+3]);
    pep[4+q][0] = pk2(pn1[4*q+0], pn1[4*q+1]);
    pep[4+q][1] = pk2(pn1[4*q+2], pn1[4*q+3]);
  }

  // a0 = q[n] - k[m] + pos_enc   (gathers read inline, sorted space)
  f32x16 av0, av1;
  #pragma unroll
  for (int mt = 0; mt < 2; ++mt) {
    f32x16& dst = mt ? av1 : av0;
    const f32x16& pn = mt ? pn1 : pn0;
    #pragma unroll
    for (int q = 0; q < 4; ++q) {
      uint2 qq_ = qT[(size_t)s * 16 + 8 * mt + 2 * q + h];
      uint2 kq_ = kT[ms * 16 + 8 * mt + 2 * q + h];
      dst[4*q+0] = pn[4*q+0] + blo(qq_.x) - blo(kq_.x);
      dst[4*q+1] = pn[4*q+1] + bhi(qq_.x) - bhi(kq_.x);
      dst[4*q+2] = pn[4*q+2] + blo(qq_.y) - blo(kq_.y);
      dst[4*q+3] = pn[4*q+3] + bhi(qq_.y) - bhi(kq_.y);
    }
  }
  buildB(av0, av1, h, Bp);

  // L2: a1 = lrelu(s*Wg1@a0 + bg1)
  acc0 = (f32x16){}; acc1 = (f32x16){};
  #pragma unroll
  for (int t = 0; t < 4; ++t) {
    acc0 = MF(sA[512 + t * 64 + lane], Bp[t], acc0);
    acc1 = MF(sA[512 + (4 + t) * 64 + lane], Bp[t], acc1);
  }
  f32x16 a10 = biasAct(acc0, bpg1, 0, h);
  f32x16 a11 = biasAct(acc1, bpg1, 1, h);
  buildB(a10, a11, h, Bp);

  // L3: a2 = lrelu(s'*Wg2@a1 + bg2')   (RSQN pre-folded)
  acc0 = (f32x16){}; acc1 = (f32x16){};
  #pragma unroll
  for (int t = 0; t < 4; ++t) {
    acc0 = MF(sA[1024 + t * 64 + lane], Bp[t], acc0);
    acc1 = MF(sA[1024 + (4 + t) * 64 + lane], Bp[t], acc1);
  }
  f32x16 at0 = biasAct(acc0, bpg2, 0, h);
  f32x16 at1 = biasAct(acc1, bpg2, 1, h);

  // softmax over kk (DPP rotate-reduce) + weighted sum of vpe = v + pos_enc (v read inline)
  uint2* rp = res_ws + ((size_t)b * N + orig) * 16;
  #pragma unroll
  for (int mt = 0; mt < 2; ++mt) {
    const f32x16& at = mt ? at1 : at0;
    f32x16 ev, nm;
    #pragma unroll
    for (int q = 0; q < 4; ++q) {
      uint2 vq_ = vT[ms * 16 + 8 * mt + 2 * q + h];
      unsigned pp0 = pep[mt * 4 + q][0], pp1 = pep[mt * 4 + q][1];
      float vp0 = blo(vq_.x) + blo(pp0);
      float vp1 = bhi(vq_.x) + bhi(pp0);
      float vp2 = blo(vq_.y) + blo(pp1);
      float vp3 = bhi(vq_.y) + bhi(pp1);
      ev[4*q+0] = __expf(at[4*q+0]); nm[4*q+0] = ev[4*q+0] * vp0;
      ev[4*q+1] = __expf(at[4*q+1]); nm[4*q+1] = ev[4*q+1] * vp1;
      ev[4*q+2] = __expf(at[4*q+2]); nm[4*q+2] = ev[4*q+2] * vp2;
      ev[4*q+3] = __expf(at[4*q+3]); nm[4*q+3] = ev[4*q+3] * vp3;
    }
    #pragma unroll
    for (int i = 0; i < 16; ++i) {
      ev[i] = rsum16(ev[i]);
      nm[i] = rsum16(nm[i]);
    }
    if (kk == 0) {
      #pragma unroll
      for (int q = 0; q < 4; ++q) {
        uint2 rr;
        rr.x = pk2(nm[4*q+0] / ev[4*q+0], nm[4*q+1] / ev[4*q+1]);
        rr.y = pk2(nm[4*q+2] / ev[4*q+2], nm[4*q+3] / ev[4*q+3]);
        rp[8 * mt + 2 * q + h] = rr;
      }
    }
  }
}

// ---------------- final (MFMA): out = lrelu(bn(W2@res)) + feats ----------------
__global__ __launch_bounds__(256) void final_kernel(
    const uint2* __restrict__ res_ws, const int4* __restrict__ AF,
    const float* __restrict__ b2p, const float* __restrict__ feats,
    float* __restrict__ out)
{
  __shared__ int4 sA[512];
  for (int i = threadIdx.x; i < 512; i += 256) sA[i] = AF[i];
  __syncthreads();
  int lane = threadIdx.x & 63, w = threadIdx.x >> 6;
  int gw = blockIdx.x * 4 + w;
  int col = lane & 31, h = lane >> 5;
  int nb = gw * 32;
  int b = nb >> 13;
  int n = (nb & (N - 1)) + col;
  size_t g = (size_t)b * N + n;
  const int4* rp = (const int4*)(res_ws + (size_t)g * 16);
  Frag Br[4];
  #pragma unroll
  for (int t = 0; t < 4; ++t) Br[t].i4 = rp[2 * t + h];
  f32x16 a0 = {}, a1 = {};
  #pragma unroll
  for (int t = 0; t < 4; ++t) {
    a0 = MF(sA[t * 64 + lane], Br[t], a0);
    a1 = MF(sA[(4 + t) * 64 + lane], Br[t], a1);
  }
  const float4* bp = (const float4*)b2p;
  f32x16 o0 = biasAct(a0, bp, 0, h);
  f32x16 o1 = biasAct(a1, bp, 1, h);
  const float* fb = feats + (size_t)b * D * N;
  float* ob = out + (size_t)b * D * N;
  #pragma unroll
  for (int mt = 0; mt < 2; ++mt) {
    const f32x16& oo = mt ? o1 : o0;
    #pragma unroll
    for (int q = 0; q < 4; ++q) {
      #pragma unroll
      for (int j = 0; j < 4; ++j) {
        int chan = 32 * mt + 8 * q + 4 * h + j;
        ob[(size_t)chan * N + n] = oo[4*q+j] + fb[(size_t)chan * N + n];
      }
    }
  }
}

} // namespace

extern "C" void kernel_launch(void* const* d_in, const int* in_sizes, int n_in,
                              void* d_out, int out_size, void* d_ws, size_t ws_size,
                              hipStream_t stream) {
  const float* feats = (const float*)d_in[0];
  const float* pos   = (const float*)d_in[1];
  const float* W1  = (const float*)d_in[3];
  const float* g1  = (const float*)d_in[4];
  const float* b1  = (const float*)d_in[5];
  const float* Wq  = (const float*)d_in[6];
  const float* Wk  = (const float*)d_in[7];
  const float* Wv  = (const float*)d_in[8];
  const float* Wd1 = (const float*)d_in[9];
  const float* gd1 = (const float*)d_in[10];
  const float* bd1 = (const float*)d_in[11];
  const float* Wd2 = (const float*)d_in[12];
  const float* gd2 = (const float*)d_in[13];
  const float* bd2 = (const float*)d_in[14];
  const float* Wg1 = (const float*)d_in[15];
  const float* gg1 = (const float*)d_in[16];
  const float* bg1 = (const float*)d_in[17];
  const float* Wg2 = (const float*)d_in[18];
  const float* gg2 = (const float*)d_in[19];
  const float* bg2 = (const float*)d_in[20];
  const float* W2  = (const float*)d_in[21];
  const float* g2  = (const float*)d_in[22];
  const float* b2  = (const float*)d_in[23];

  uint8_t* wsb = (uint8_t*)d_ws;
  unsigned short* AF = (unsigned short*)wsb;               // bf16 A-frags (73728 B reserved)
  float* biasAll = (float*)(wsb + 73728);                  // 320 floats
  float* pos4    = (float*)(wsb + 75008);                  // 65536 floats (256 KB)
  uint2* qTb     = (uint2*)(wsb + 337152);                 // 2 MB (sorted-slot layout)
  uint2* kTb     = (uint2*)(wsb + 2434304);                // 2 MB
  uint2* vTb     = (uint2*)(wsb + 4531456);                // 2 MB
  uint2* res_ws  = (uint2*)(wsb + 6628608);                // 2 MB (bf16-packed; 4 MB reserved)
  int*   cid16     = (int*)(wsb + 10822912);               // 64 KB
  int*   cellCount = (int*)(wsb + 10888448);               // 8 KB (2048)
  int*   cellStart = (int*)(wsb + 10896640);               // 8 KB (2048+1)
  int*   cellOfs   = (int*)(wsb + 10904832);               // 8 KB (2048)
  float4* pos4s    = (float4*)(wsb + 10913024);            // 256 KB
  int*   sid       = (int*)(wsb + 11175168);               // 64 KB
  int*   knn_s     = (int*)(wsb + 11240704);               // 1 MB (16384*16*4)
  int*   inv       = (int*)(wsb + 12289280);               // 64 KB
  int*   workCtr   = (int*)(wsb + 12355072);               // 4 B

  PrepArgs pa;
  pa.W[0] = W1;  pa.W[1] = Wq;  pa.W[2] = Wk;  pa.W[3] = Wv;
  pa.W[4] = Wd2; pa.W[5] = Wg1; pa.W[6] = Wg2; pa.W[7] = W2; pa.W[8] = Wd1;
  pa.scale[0] = g1;  pa.scale[1] = nullptr; pa.scale[2] = nullptr; pa.scale[3] = nullptr;
  pa.scale[4] = gd2; pa.scale[5] = gg1;     pa.scale[6] = gg2;     pa.scale[7] = g2; pa.scale[8] = gd1;
  pa.bias[0] = b1; pa.bias[1] = bd2; pa.bias[2] = bg1; pa.bias[3] = bg2; pa.bias[4] = b2;
  pa.bd1 = bd1;

  hipMemsetAsync(cellCount, 0, 2048 * sizeof(int), stream);
  hipMemsetAsync(cellOfs, 0, 2048 * sizeof(int), stream);
  hipMemsetAsync(workCtr, 0, sizeof(int), stream);
  hipLaunchKernelGGL(prep_kernel, dim3(9), dim3(256), 0, stream, pa, AF, biasAll);
  hipLaunchKernelGGL(pos4cid_kernel, dim3(B * N / 256), dim3(256), 0, stream,
                     pos, pos4, cid16, cellCount);
  hipLaunchKernelGGL(scan_kernel, dim3(1), dim3(1024), 0, stream, cellCount, cellStart);
  hipLaunchKernelGGL(scatter_kernel, dim3(B * N / 256), dim3(256), 0, stream,
                     pos4, cid16, cellStart, cellOfs, pos4s, sid, inv);
  hipLaunchKernelGGL(knn_shell_kernel, dim3(512), dim3(256), 0, stream,
                     pos4s, sid, cellStart, knn_s, workCtr);
  hipLaunchKernelGGL(qkv_kernel, dim3(128, 3), dim3(256), 0, stream,
                     feats, (const int4*)wsb, biasAll, inv, qTb, kTb, vTb);
  hipLaunchKernelGGL(fused_kernel, dim3(B * N / 8), dim3(256), 0, stream,
                     pos4s, sid, knn_s, qTb, kTb, vTb,
                     (const int4*)(wsb + 32768), biasAll + 64, res_ws);
  hipLaunchKernelGGL(final_kernel, dim3(128), dim3(256), 0, stream,
                     res_ws, (const int4*)(wsb + 59392), biasAll + 256, feats, (float*)d_out);
}

// Round 13
// 144.563 us; speedup vs baseline: 1.3926x; 1.3926x over previous
//
#include <hip/hip_runtime.h>
#include <hip/hip_bf16.h>
#include <math.h>

namespace {

constexpr int B = 2;
constexpr int N = 8192;
constexpr int D = 64;
constexpr int GRID = 10;
constexpr int GC = GRID * GRID * GRID;     // 1000 cells per batch
constexpr float H = 0.1f;
constexpr float NEGS = 0.2f;
constexpr float BN_INV = 0.9999950000374997f;   // 1/sqrt(1+1e-5)
constexpr float RSQN = 0.011048543456039806f;   // 1/sqrt(8192)
constexpr int KNN_BLOCKS = B * N / 16;     // 1024 (16 lanes per query, 256 thr/blk)

typedef __attribute__((ext_vector_type(8))) short bf16x8;
typedef __attribute__((ext_vector_type(16))) float f32x16;

union Frag { int4 i4; unsigned u[4]; bf16x8 h; };

__device__ __forceinline__ float lrelu(float v) { return fmaxf(v, NEGS * v); }

__device__ __forceinline__ unsigned pk2(float a, float b) {
  __hip_bfloat162 h2 = __float22bfloat162_rn(make_float2(a, b));
  unsigned r;
  __builtin_memcpy(&r, &h2, 4);
  return r;
}
__device__ __forceinline__ float blo(unsigned u) { return __uint_as_float(u << 16); }
__device__ __forceinline__ float bhi(unsigned u) { return __uint_as_float(u & 0xFFFF0000u); }

__device__ __forceinline__ f32x16 MF(int4 a, const Frag& b, f32x16 c) {
  Frag af; af.i4 = a;
  return __builtin_amdgcn_mfma_f32_32x32x16_bf16(af.h, b.h, c, 0, 0, 0);
}

// 16-lane-row reductions via DPP row_ror (pure VALU, no DS pipe).
template <int CTRL>
__device__ __forceinline__ float dpp_add(float v) {
  int t = __builtin_amdgcn_update_dpp(0, __float_as_int(v), CTRL, 0xF, 0xF, false);
  return v + __int_as_float(t);
}
__device__ __forceinline__ float rsum16(float v) {
  v = dpp_add<0x128>(v);   // row_ror:8
  v = dpp_add<0x124>(v);   // row_ror:4
  v = dpp_add<0x122>(v);   // row_ror:2
  v = dpp_add<0x121>(v);   // row_ror:1
  return v;
}
template <int CTRL>
__device__ __forceinline__ unsigned long long dpp_min_u64(unsigned long long k) {
  int lo = __builtin_amdgcn_update_dpp(0, (int)(unsigned)k, CTRL, 0xF, 0xF, false);
  int hi = __builtin_amdgcn_update_dpp(0, (int)(unsigned)(k >> 32), CTRL, 0xF, 0xF, false);
  unsigned long long o = ((unsigned long long)(unsigned)hi << 32) | (unsigned)lo;
  return o < k ? o : k;
}
__device__ __forceinline__ unsigned long long rmin16_u64(unsigned long long k) {
  k = dpp_min_u64<0x128>(k);
  k = dpp_min_u64<0x124>(k);
  k = dpp_min_u64<0x122>(k);
  k = dpp_min_u64<0x121>(k);
  return k;
}

__device__ __forceinline__ int cellco(float v) {
  int c = (int)(v * 10.0f);
  return min(max(c, 0), GRID - 1);
}

// D-layout f32 (x0: chans 0-31 rows, x1: chans 32-63) -> B-fragments for next layer.
__device__ __forceinline__ void buildB(const f32x16& x0, const f32x16& x1, int h, Frag Bf[4]) {
  unsigned Z[8][2];
  #pragma unroll
  for (int q = 0; q < 4; ++q) {
    Z[q][0]     = pk2(x0[4*q+0], x0[4*q+1]);
    Z[q][1]     = pk2(x0[4*q+2], x0[4*q+3]);
    Z[4+q][0]   = pk2(x1[4*q+0], x1[4*q+1]);
    Z[4+q][1]   = pk2(x1[4*q+2], x1[4*q+3]);
  }
  unsigned S[8][2];
  #pragma unroll
  for (int q = 0; q < 8; ++q) {
    S[q][0] = (unsigned)__shfl_xor((int)Z[q][0], 32);
    S[q][1] = (unsigned)__shfl_xor((int)Z[q][1], 32);
  }
  #pragma unroll
  for (int t = 0; t < 4; ++t) {
    int qq = (t >> 1) * 4 + 2 * (t & 1);
    Bf[t].u[0] = h ? S[qq+1][0] : Z[qq][0];
    Bf[t].u[1] = h ? S[qq+1][1] : Z[qq][1];
    Bf[t].u[2] = h ? Z[qq+1][0] : S[qq][0];
    Bf[t].u[3] = h ? Z[qq+1][1] : S[qq][1];
  }
}

__device__ __forceinline__ f32x16 biasAct(f32x16 d, const float4* bp, int mt, int h) {
  f32x16 r;
  #pragma unroll
  for (int q = 0; q < 4; ++q) {
    float4 bb = bp[h * 8 + mt * 4 + q];
    r[4*q+0] = lrelu(d[4*q+0] + bb.x);
    r[4*q+1] = lrelu(d[4*q+1] + bb.y);
    r[4*q+2] = lrelu(d[4*q+2] + bb.z);
    r[4*q+3] = lrelu(d[4*q+3] + bb.w);
  }
  return r;
}

// ---------------- prep: pack A-fragments (bf16, BN scale folded; Wg2 also folds RSQN) ----------------
struct PrepArgs {
  const float* W[9];       // W1,Wq,Wk,Wv,Wd2,Wg1,Wg2,W2,Wd1
  const float* scale[9];
  const float* bias[5];    // b1,bd2,bg1,bg2,b2
  const float* bd1;
};

__global__ __launch_bounds__(256) void prep_kernel(PrepArgs a, unsigned short* AF, float* biasAll) {
  int mi = blockIdx.x;
  int tid = threadIdx.x;
  if (mi < 8) {
    int off = (mi == 7) ? 29696 : mi * 4096;
    const float* W = a.W[mi];
    const float* G = a.scale[mi];
    unsigned short* dst = AF + off;
    for (int e = tid; e < 4096; e += 256) {
      int i = e & 7, lane = (e >> 3) & 63, t = (e >> 9) & 3, mt = e >> 11;
      int row = 32 * mt + (lane & 31);
      int k = 16 * t + 8 * (lane >> 5) + i;
      float v = W[row * 64 + k];
      if (G) v *= G[row] * BN_INV;
      if (mi == 6) v *= RSQN;                  // fold 1/sqrt(N) into Wg2
      __hip_bfloat16 hb = __float2bfloat16(v);
      __builtin_memcpy(&dst[e], &hb, 2);
    }
  } else {
    const float* W = a.W[8];
    const float* G = a.scale[8];
    for (int e = tid; e < 1024; e += 256) {
      int i = e & 7, lane = (e >> 3) & 63, mt = e >> 9;
      int row = 32 * mt + (lane & 31), h = lane >> 5;
      float v = 0.f;
      if (h == 0) {
        if (i < 3) v = W[row * 3 + i] * G[row] * BN_INV;
        else if (i == 3) v = a.bd1[row];
      }
      __hip_bfloat16 hb = __float2bfloat16(v);
      __builtin_memcpy(&AF[28672 + e], &hb, 2);
    }
    for (int e = tid; e < 320; e += 256) {
      int ai = e >> 6, idx = e & 63;
      int h = idx >> 5, mt = (idx >> 4) & 1, q = (idx >> 2) & 3, j = idx & 3;
      float bv = a.bias[ai][32 * mt + 8 * q + 4 * h + j];
      if (ai == 3) bv *= RSQN;                 // fold 1/sqrt(N) into bg2
      biasAll[e] = bv;
    }
  }
}

// ---------------- pos4 + cell id + histogram ----------------
__global__ __launch_bounds__(256) void pos4cid_kernel(
    const float* __restrict__ pos, float* __restrict__ pos4,
    int* __restrict__ cid16, int* __restrict__ cellCount)
{
  int i = blockIdx.x * 256 + threadIdx.x;
  int b = i >> 13;
  int n = i & (N - 1);
  const float* pb = pos + (size_t)b * 3 * N;
  float x = pb[n], y = pb[N + n], z = pb[2 * N + n];
  float4 v = {x, y, z, x * x + y * y + z * z};
  *reinterpret_cast<float4*>(pos4 + (size_t)i * 4) = v;
  int cid = (cellco(z) * GRID + cellco(y)) * GRID + cellco(x);
  cid16[i] = cid;
  atomicAdd(&cellCount[b * GC + cid], 1);
}

// ---------------- scan: exclusive prefix over 2048 cell counts (single block) ----------------
__global__ __launch_bounds__(1024) void scan_kernel(
    const int* __restrict__ cnt, int* __restrict__ cellStart)
{
  __shared__ int s[2][2048];
  int t = threadIdx.x;
  s[0][t] = cnt[t];
  s[0][t + 1024] = cnt[t + 1024];
  __syncthreads();
  int src = 0;
  for (int off = 1; off < 2048; off <<= 1) {
    int dst = src ^ 1;
    for (int i = t; i < 2048; i += 1024) {
      int v = s[src][i];
      if (i >= off) v += s[src][i - off];
      s[dst][i] = v;
    }
    __syncthreads();
    src ^= 1;
  }
  cellStart[t] = (t == 0) ? 0 : s[src][t - 1];
  cellStart[t + 1024] = s[src][t + 1023];
}

// ---------------- scatter: counting-sort points by cell (+ inverse map orig->sorted) ----------------
__global__ __launch_bounds__(256) void scatter_kernel(
    const float* __restrict__ pos4, const int* __restrict__ cid16,
    const int* __restrict__ cellStart, int* __restrict__ cellOfs,
    float4* __restrict__ pos4s, int* __restrict__ sid, int* __restrict__ inv)
{
  int i = blockIdx.x * 256 + threadIdx.x;
  int b = i >> 13;
  int cg = b * GC + cid16[i];
  int dst = cellStart[cg] + atomicAdd(&cellOfs[cg], 1);
  pos4s[dst] = *reinterpret_cast<const float4*>(pos4 + (size_t)i * 4);
  sid[dst] = i & (N - 1);
  inv[i] = dst;                                // global sorted slot of orig point
}

// ---------------- knn + qkv fat kernel: blocks [0,1024) = knn, [1024,1408) = qkv ----------------
// knn: 16-lane group per query, static mapping (4096 waves), adaptive initial radius
// (r0=2 when >=2 cell coords are boundary -> clipped-ball queries skip the doomed r=1 pass).
// qkv: MFMA path; backfills SIMDs as knn's long-pole waves drain (VALU/MFMA pipes overlap).
__global__ __launch_bounds__(256) void knnqkv_kernel(
    const float4* __restrict__ pos4s, const int* __restrict__ sid,
    const int* __restrict__ cellStart, int* __restrict__ knn_s,
    const float* __restrict__ feats, const int4* __restrict__ AF,
    const float* __restrict__ b1p, const int* __restrict__ inv,
    uint2* __restrict__ qT, uint2* __restrict__ kT, uint2* __restrict__ vT)
{
  __shared__ int4 sA[1024];

  if (blockIdx.x < KNN_BLOCKS) {
    // ---------------- knn path ----------------
    constexpr unsigned long long SENT = ~0ULL;
    int lq = threadIdx.x & 15;
    int wid = (blockIdx.x * 256 + threadIdx.x) >> 4;   // query = global sorted slot
    int b = wid >> 13;
    float4 q = pos4s[wid];
    int cx = cellco(q.x), cy = cellco(q.y), cz = cellco(q.z);
    const int cbase = b * GC;
    int myout = 0;

    int nb = (int)(cx == 0 || cx == GRID - 1) + (int)(cy == 0 || cy == GRID - 1)
           + (int)(cz == 0 || cz == GRID - 1);
    int r0 = (nb >= 2) ? 2 : 1;                        // group-uniform

    bool done = false;
    #pragma unroll 1
    for (int r = r0; r < GRID; ++r) {
      if (!done) {
        unsigned long long dk[16];
        #pragma unroll
        for (int j = 0; j < 16; ++j) dk[j] = SENT;

        int x0 = max(cx - r, 0), x1 = min(cx + r, GRID - 1);
        int y0 = max(cy - r, 0), y1 = min(cy + r, GRID - 1);
        int z0 = max(cz - r, 0), z1 = min(cz + r, GRID - 1);
        #pragma unroll 1
        for (int zz = z0; zz <= z1; ++zz) {
          #pragma unroll 1
          for (int yy = y0; yy <= y1; ++yy) {
            int rowc = cbase + (zz * GRID + yy) * GRID;
            int i0 = cellStart[rowc + x0], i1 = cellStart[rowc + x1 + 1];
            #pragma unroll 1
            for (int i = i0 + lq; i < i1; i += 16) {
              float4 cp = pos4s[i];
              float inn = q.x * cp.x + q.y * cp.y + q.z * cp.z;
              float dist = fmaxf(fmaf(-2.f, inn, q.w + cp.w), 0.f);
              unsigned long long key =
                  ((unsigned long long)__float_as_uint(dist) << 26) |
                  ((unsigned long long)(unsigned)sid[i] << 13) |
                  (unsigned long long)(unsigned)(i & (N - 1));
              if (key < dk[15]) {
                bool bj = true;
                #pragma unroll
                for (int j = 15; j >= 1; --j) {
                  bool bjm1 = key < dk[j - 1];
                  dk[j] = bj ? (bjm1 ? dk[j - 1] : key) : dk[j];
                  bj = bjm1;
                }
                if (bj) dk[0] = key;
              }
            }
          }
        }

        // extract group top-16 via DPP u64 min; round-e winner kept by lane e
        float dlast = 0.f;
        #pragma unroll 1
        for (int e = 0; e < 16; ++e) {
          unsigned long long m = rmin16_u64(dk[0]);
          if (dk[0] == m) {                      // unique winner (keys embed unique ids)
            #pragma unroll
            for (int j = 0; j < 15; ++j) dk[j] = dk[j + 1];
            dk[15] = SENT;
          }
          if (lq == e) myout = (int)(m & 0x1FFFULL);
          dlast = __uint_as_float((unsigned)(m >> 26));
        }

        // margin certificate from searched window (domain faces -> inf)
        float mg = 3.4e38f;
        if (cx - r > 0)        mg = fminf(mg, q.x - (cx - r) * H);
        if (cx + r < GRID - 1) mg = fminf(mg, (cx + r + 1) * H - q.x);
        if (cy - r > 0)        mg = fminf(mg, q.y - (cy - r) * H);
        if (cy + r < GRID - 1) mg = fminf(mg, (cy + r + 1) * H - q.y);
        if (cz - r > 0)        mg = fminf(mg, q.z - (cz - r) * H);
        if (cz + r < GRID - 1) mg = fminf(mg, (cz + r + 1) * H - q.z);
        done = (dlast <= mg * mg * 0.999f);      // group-uniform
      }
      if (__all(done)) break;
    }

    knn_s[(size_t)wid * 16 + lq] = myout;        // one coalesced store per group
    return;
  }

  // ---------------- qkv path ----------------
  int qb = blockIdx.x - KNN_BLOCKS;
  int my = qb >> 7;                              // output matrix 0..2
  int gx = qb & 127;
  for (int i = threadIdx.x; i < 512; i += 256) {
    sA[i] = AF[i];
    sA[512 + i] = AF[512 * (1 + my) + i];
  }
  __syncthreads();
  int lane = threadIdx.x & 63, w = threadIdx.x >> 6;
  int gw = gx * 4 + w;
  int col = lane & 31, h = lane >> 5;
  int nb_ = gw * 32;
  int b = nb_ >> 13;
  int n = (nb_ & (N - 1)) + col;
  size_t gpt = (size_t)b * N + n;
  int sv = inv[gpt];                             // sorted slot (coalesced read)
  const float* fb = feats + (size_t)b * D * N + n;

  Frag Bf[4];
  #pragma unroll
  for (int t = 0; t < 4; ++t) {
    int c0 = 16 * t + 8 * h;
    float f[8];
    #pragma unroll
    for (int i = 0; i < 8; ++i) f[i] = fb[(size_t)(c0 + i) * N];
    #pragma unroll
    for (int d_ = 0; d_ < 4; ++d_) Bf[t].u[d_] = pk2(f[2*d_], f[2*d_+1]);
  }
  f32x16 acc0 = {}, acc1 = {};
  #pragma unroll
  for (int t = 0; t < 4; ++t) {
    acc0 = MF(sA[t * 64 + lane], Bf[t], acc0);
    acc1 = MF(sA[(4 + t) * 64 + lane], Bf[t], acc1);
  }
  const float4* bp = (const float4*)b1p;
  f32x16 x0 = biasAct(acc0, bp, 0, h);
  f32x16 x1 = biasAct(acc1, bp, 1, h);
  Frag Bx[4];
  buildB(x0, x1, h, Bx);

  uint2* op = (my == 0) ? qT : (my == 1) ? kT : vT;
  f32x16 a0 = {}, a1 = {};
  #pragma unroll
  for (int t = 0; t < 4; ++t) {
    a0 = MF(sA[512 + t * 64 + lane], Bx[t], a0);
    a1 = MF(sA[512 + (4 + t) * 64 + lane], Bx[t], a1);
  }
  #pragma unroll
  for (int q = 0; q < 4; ++q) {
    uint2 v0, v1;
    v0.x = pk2(a0[4*q+0], a0[4*q+1]); v0.y = pk2(a0[4*q+2], a0[4*q+3]);
    v1.x = pk2(a1[4*q+0], a1[4*q+1]); v1.y = pk2(a1[4*q+2], a1[4*q+3]);
    op[(size_t)sv * 16 + 2 * q + h] = v0;        // scatter write to sorted slot
    op[(size_t)sv * 16 + 8 + 2 * q + h] = v1;
  }
}

// ---------------- fused (MFMA): LDS weights; inline sorted-space gathers; DPP softmax ----------------
__global__ __launch_bounds__(256) void fused_kernel(
    const float4* __restrict__ pos4s, const int* __restrict__ sid,
    const int* __restrict__ knn_s,
    const uint2* __restrict__ qT, const uint2* __restrict__ kT, const uint2* __restrict__ vT,
    const int4* __restrict__ AF,      // [Wd2 | Wg1 | Wg2 | Wd1]
    const float* __restrict__ biases, // bd2p | bg1p | bg2p(RSQN-folded)
    uint2* __restrict__ res_ws)       // bf16-packed res, orig order, B-frag pair layout
{
  int lane = threadIdx.x & 63, w = threadIdx.x >> 6;
  int gw = blockIdx.x * 4 + w;
  int col = lane & 31, h = lane >> 5;
  int p = col >> 4, kk = col & 15;
  int sbase = gw * 2;
  int b = sbase >> 13;
  int s = sbase + p;                            // global sorted slot of own point

  // point-level loads issued before LDS stage (hide under stage+barrier)
  int m_loc = knn_s[(size_t)s * 16 + kk];       // sorted-local neighbor idx (coalesced)
  int orig = sid[s];
  float4 P = pos4s[s];

  __shared__ int4 sA[1664];
  for (int i = threadIdx.x; i < 1664; i += 256) sA[i] = AF[i];
  __syncthreads();
  const float4* bpd2 = (const float4*)(biases);
  const float4* bpg1 = (const float4*)(biases + 64);
  const float4* bpg2 = (const float4*)(biases + 128);

  size_t ms = (size_t)b * N + m_loc;            // global sorted neighbor slot
  float4 Q = pos4s[ms];
  float rx = P.x - Q.x, ry = P.y - Q.y, rz = P.z - Q.z;

  // L0: pe = lrelu(s*Wd1@rel + bd1)   (bias via B k=3 column)
  Frag B0;
  B0.u[0] = h ? 0u : pk2(rx, ry);
  B0.u[1] = h ? 0u : pk2(rz, 1.0f);
  B0.u[2] = 0u; B0.u[3] = 0u;
  f32x16 acc0 = {}, acc1 = {};
  acc0 = MF(sA[1536 + lane], B0, acc0);
  acc1 = MF(sA[1600 + lane], B0, acc1);
  f32x16 pe0, pe1;
  #pragma unroll
  for (int i = 0; i < 16; ++i) { pe0[i] = lrelu(acc0[i]); pe1[i] = lrelu(acc1[i]); }
  Frag Bp[4];
  buildB(pe0, pe1, h, Bp);

  // L1: pos_enc = lrelu(s*Wd2@pe + bd2)
  acc0 = (f32x16){}; acc1 = (f32x16){};
  #pragma unroll
  for (int t = 0; t < 4; ++t) {
    acc0 = MF(sA[t * 64 + lane], Bp[t], acc0);
    acc1 = MF(sA[(4 + t) * 64 + lane], Bp[t], acc1);
  }
  f32x16 pn0 = biasAct(acc0, bpd2, 0, h);
  f32x16 pn1 = biasAct(acc1, bpd2, 1, h);

  unsigned pep[8][2];
  #pragma unroll
  for (int q = 0; q < 4; ++q) {
    pep[q][0]   = pk2(pn0[4*q+0], pn0[4*q+1]);
    pep[q][1]   = pk2(pn0[4*q+2], pn0[4*q+3]);
    pep[4+q][0] = pk2(pn1[4*q+0], pn1[4*q+1]);
    pep[4+q][1] = pk2(pn1[4*q+2], pn1[4*q+3]);
  }

  // a0 = q[n] - k[m] + pos_enc   (gathers read inline, sorted space)
  f32x16 av0, av1;
  #pragma unroll
  for (int mt = 0; mt < 2; ++mt) {
    f32x16& dst = mt ? av1 : av0;
    const f32x16& pn = mt ? pn1 : pn0;
    #pragma unroll
    for (int q = 0; q < 4; ++q) {
      uint2 qq_ = qT[(size_t)s * 16 + 8 * mt + 2 * q + h];
      uint2 kq_ = kT[ms * 16 + 8 * mt + 2 * q + h];
      dst[4*q+0] = pn[4*q+0] + blo(qq_.x) - blo(kq_.x);
      dst[4*q+1] = pn[4*q+1] + bhi(qq_.x) - bhi(kq_.x);
      dst[4*q+2] = pn[4*q+2] + blo(qq_.y) - blo(kq_.y);
      dst[4*q+3] = pn[4*q+3] + bhi(qq_.y) - bhi(kq_.y);
    }
  }
  buildB(av0, av1, h, Bp);

  // L2: a1 = lrelu(s*Wg1@a0 + bg1)
  acc0 = (f32x16){}; acc1 = (f32x16){};
  #pragma unroll
  for (int t = 0; t < 4; ++t) {
    acc0 = MF(sA[512 + t * 64 + lane], Bp[t], acc0);
    acc1 = MF(sA[512 + (4 + t) * 64 + lane], Bp[t], acc1);
  }
  f32x16 a10 = biasAct(acc0, bpg1, 0, h);
  f32x16 a11 = biasAct(acc1, bpg1, 1, h);
  buildB(a10, a11, h, Bp);

  // L3: a2 = lrelu(s'*Wg2@a1 + bg2')   (RSQN pre-folded)
  acc0 = (f32x16){}; acc1 = (f32x16){};
  #pragma unroll
  for (int t = 0; t < 4; ++t) {
    acc0 = MF(sA[1024 + t * 64 + lane], Bp[t], acc0);
    acc1 = MF(sA[1024 + (4 + t) * 64 + lane], Bp[t], acc1);
  }
  f32x16 at0 = biasAct(acc0, bpg2, 0, h);
  f32x16 at1 = biasAct(acc1, bpg2, 1, h);

  // softmax over kk (DPP rotate-reduce) + weighted sum of vpe = v + pos_enc (v read inline)
  uint2* rp = res_ws + ((size_t)b * N + orig) * 16;
  #pragma unroll
  for (int mt = 0; mt < 2; ++mt) {
    const f32x16& at = mt ? at1 : at0;
    f32x16 ev, nm;
    #pragma unroll
    for (int q = 0; q < 4; ++q) {
      uint2 vq_ = vT[ms * 16 + 8 * mt + 2 * q + h];
      unsigned pp0 = pep[mt * 4 + q][0], pp1 = pep[mt * 4 + q][1];
      float vp0 = blo(vq_.x) + blo(pp0);
      float vp1 = bhi(vq_.x) + bhi(pp0);
      float vp2 = blo(vq_.y) + blo(pp1);
      float vp3 = bhi(vq_.y) + bhi(pp1);
      ev[4*q+0] = __expf(at[4*q+0]); nm[4*q+0] = ev[4*q+0] * vp0;
      ev[4*q+1] = __expf(at[4*q+1]); nm[4*q+1] = ev[4*q+1] * vp1;
      ev[4*q+2] = __expf(at[4*q+2]); nm[4*q+2] = ev[4*q+2] * vp2;
      ev[4*q+3] = __expf(at[4*q+3]); nm[4*q+3] = ev[4*q+3] * vp3;
    }
    #pragma unroll
    for (int i = 0; i < 16; ++i) {
      ev[i] = rsum16(ev[i]);
      nm[i] = rsum16(nm[i]);
    }
    if (kk == 0) {
      #pragma unroll
      for (int q = 0; q < 4; ++q) {
        uint2 rr;
        rr.x = pk2(nm[4*q+0] / ev[4*q+0], nm[4*q+1] / ev[4*q+1]);
        rr.y = pk2(nm[4*q+2] / ev[4*q+2], nm[4*q+3] / ev[4*q+3]);
        rp[8 * mt + 2 * q + h] = rr;
      }
    }
  }
}

// ---------------- final (MFMA): out = lrelu(bn(W2@res)) + feats ----------------
__global__ __launch_bounds__(256) void final_kernel(
    const uint2* __restrict__ res_ws, const int4* __restrict__ AF,
    const float* __restrict__ b2p, const float* __restrict__ feats,
    float* __restrict__ out)
{
  __shared__ int4 sA[512];
  for (int i = threadIdx.x; i < 512; i += 256) sA[i] = AF[i];
  __syncthreads();
  int lane = threadIdx.x & 63, w = threadIdx.x >> 6;
  int gw = blockIdx.x * 4 + w;
  int col = lane & 31, h = lane >> 5;
  int nb = gw * 32;
  int b = nb >> 13;
  int n = (nb & (N - 1)) + col;
  size_t g = (size_t)b * N + n;
  const int4* rp = (const int4*)(res_ws + (size_t)g * 16);
  Frag Br[4];
  #pragma unroll
  for (int t = 0; t < 4; ++t) Br[t].i4 = rp[2 * t + h];
  f32x16 a0 = {}, a1 = {};
  #pragma unroll
  for (int t = 0; t < 4; ++t) {
    a0 = MF(sA[t * 64 + lane], Br[t], a0);
    a1 = MF(sA[(4 + t) * 64 + lane], Br[t], a1);
  }
  const float4* bp = (const float4*)b2p;
  f32x16 o0 = biasAct(a0, bp, 0, h);
  f32x16 o1 = biasAct(a1, bp, 1, h);
  const float* fb = feats + (size_t)b * D * N;
  float* ob = out + (size_t)b * D * N;
  #pragma unroll
  for (int mt = 0; mt < 2; ++mt) {
    const f32x16& oo = mt ? o1 : o0;
    #pragma unroll
    for (int q = 0; q < 4; ++q) {
      #pragma unroll
      for (int j = 0; j < 4; ++j) {
        int chan = 32 * mt + 8 * q + 4 * h + j;
        ob[(size_t)chan * N + n] = oo[4*q+j] + fb[(size_t)chan * N + n];
      }
    }
  }
}

} // namespace

extern "C" void kernel_launch(void* const* d_in, const int* in_sizes, int n_in,
                              void* d_out, int out_size, void* d_ws, size_t ws_size,
                              hipStream_t stream) {
  const float* feats = (const float*)d_in[0];
  const float* pos   = (const float*)d_in[1];
  const float* W1  = (const float*)d_in[3];
  const float* g1  = (const float*)d_in[4];
  const float* b1  = (const float*)d_in[5];
  const float* Wq  = (const float*)d_in[6];
  const float* Wk  = (const float*)d_in[7];
  const float* Wv  = (const float*)d_in[8];
  const float* Wd1 = (const float*)d_in[9];
  const float* gd1 = (const float*)d_in[10];
  const float* bd1 = (const float*)d_in[11];
  const float* Wd2 = (const float*)d_in[12];
  const float* gd2 = (const float*)d_in[13];
  const float* bd2 = (const float*)d_in[14];
  const float* Wg1 = (const float*)d_in[15];
  const float* gg1 = (const float*)d_in[16];
  const float* bg1 = (const float*)d_in[17];
  const float* Wg2 = (const float*)d_in[18];
  const float* gg2 = (const float*)d_in[19];
  const float* bg2 = (const float*)d_in[20];
  const float* W2  = (const float*)d_in[21];
  const float* g2  = (const float*)d_in[22];
  const float* b2  = (const float*)d_in[23];

  uint8_t* wsb = (uint8_t*)d_ws;
  unsigned short* AF = (unsigned short*)wsb;               // bf16 A-frags (73728 B reserved)
  float* biasAll = (float*)(wsb + 73728);                  // 320 floats
  float* pos4    = (float*)(wsb + 75008);                  // 65536 floats (256 KB)
  uint2* qTb     = (uint2*)(wsb + 337152);                 // 2 MB (sorted-slot layout)
  uint2* kTb     = (uint2*)(wsb + 2434304);                // 2 MB
  uint2* vTb     = (uint2*)(wsb + 4531456);                // 2 MB
  uint2* res_ws  = (uint2*)(wsb + 6628608);                // 2 MB (bf16-packed; 4 MB reserved)
  int*   cid16     = (int*)(wsb + 10822912);               // 64 KB
  int*   cellCount = (int*)(wsb + 10888448);               // 8 KB (2048)
  int*   cellStart = (int*)(wsb + 10896640);               // 8 KB (2048+1)
  int*   cellOfs   = (int*)(wsb + 10904832);               // 8 KB (2048)
  float4* pos4s    = (float4*)(wsb + 10913024);            // 256 KB
  int*   sid       = (int*)(wsb + 11175168);               // 64 KB
  int*   knn_s     = (int*)(wsb + 11240704);               // 1 MB (16384*16*4)
  int*   inv       = (int*)(wsb + 12289280);               // 64 KB

  PrepArgs pa;
  pa.W[0] = W1;  pa.W[1] = Wq;  pa.W[2] = Wk;  pa.W[3] = Wv;
  pa.W[4] = Wd2; pa.W[5] = Wg1; pa.W[6] = Wg2; pa.W[7] = W2; pa.W[8] = Wd1;
  pa.scale[0] = g1;  pa.scale[1] = nullptr; pa.scale[2] = nullptr; pa.scale[3] = nullptr;
  pa.scale[4] = gd2; pa.scale[5] = gg1;     pa.scale[6] = gg2;     pa.scale[7] = g2; pa.scale[8] = gd1;
  pa.bias[0] = b1; pa.bias[1] = bd2; pa.bias[2] = bg1; pa.bias[3] = bg2; pa.bias[4] = b2;
  pa.bd1 = bd1;

  hipMemsetAsync(cellCount, 0, 2048 * sizeof(int), stream);
  hipMemsetAsync(cellOfs, 0, 2048 * sizeof(int), stream);
  hipLaunchKernelGGL(prep_kernel, dim3(9), dim3(256), 0, stream, pa, AF, biasAll);
  hipLaunchKernelGGL(pos4cid_kernel, dim3(B * N / 256), dim3(256), 0, stream,
                     pos, pos4, cid16, cellCount);
  hipLaunchKernelGGL(scan_kernel, dim3(1), dim3(1024), 0, stream, cellCount, cellStart);
  hipLaunchKernelGGL(scatter_kernel, dim3(B * N / 256), dim3(256), 0, stream,
                     pos4, cid16, cellStart, cellOfs, pos4s, sid, inv);
  hipLaunchKernelGGL(knnqkv_kernel, dim3(KNN_BLOCKS + 384), dim3(256), 0, stream,
                     pos4s, sid, cellStart, knn_s,
                     feats, (const int4*)wsb, biasAll, inv, qTb, kTb, vTb);
  hipLaunchKernelGGL(fused_kernel, dim3(B * N / 8), dim3(256), 0, stream,
                     pos4s, sid, knn_s, qTb, kTb, vTb,
                     (const int4*)(wsb + 32768), biasAll + 64, res_ws);
  hipLaunchKernelGGL(final_kernel, dim3(128), dim3(256), 0, stream,
                     res_ws, (const int4*)(wsb + 59392), biasAll + 256, feats, (float*)d_out);
}

// Round 14
// 128.175 us; speedup vs baseline: 1.5706x; 1.1279x over previous
//
#include <hip/hip_runtime.h>
#include <hip/hip_bf16.h>
#include <math.h>

namespace {

constexpr int B = 2;
constexpr int N = 8192;
constexpr int D = 64;
constexpr int GRID = 10;
constexpr int GC = GRID * GRID * GRID;     // 1000 cells per batch
constexpr float H = 0.1f;
constexpr float NEGS = 0.2f;
constexpr float BN_INV = 0.9999950000374997f;   // 1/sqrt(1+1e-5)
constexpr float RSQN = 0.011048543456039806f;   // 1/sqrt(8192)
constexpr int KNN_BLOCKS = B * N / 16;     // 1024 (16 lanes per query, 256 thr/blk)

typedef __attribute__((ext_vector_type(8))) short bf16x8;
typedef __attribute__((ext_vector_type(16))) float f32x16;

union Frag { int4 i4; unsigned u[4]; bf16x8 h; };

__device__ __forceinline__ float lrelu(float v) { return fmaxf(v, NEGS * v); }

__device__ __forceinline__ unsigned pk2(float a, float b) {
  __hip_bfloat162 h2 = __float22bfloat162_rn(make_float2(a, b));
  unsigned r;
  __builtin_memcpy(&r, &h2, 4);
  return r;
}
__device__ __forceinline__ float blo(unsigned u) { return __uint_as_float(u << 16); }
__device__ __forceinline__ float bhi(unsigned u) { return __uint_as_float(u & 0xFFFF0000u); }

__device__ __forceinline__ f32x16 MF(int4 a, const Frag& b, f32x16 c) {
  Frag af; af.i4 = a;
  return __builtin_amdgcn_mfma_f32_32x32x16_bf16(af.h, b.h, c, 0, 0, 0);
}

// 16-lane-row reductions via DPP row_ror (pure VALU, no DS pipe).
template <int CTRL>
__device__ __forceinline__ float dpp_add(float v) {
  int t = __builtin_amdgcn_update_dpp(0, __float_as_int(v), CTRL, 0xF, 0xF, false);
  return v + __int_as_float(t);
}
__device__ __forceinline__ float rsum16(float v) {
  v = dpp_add<0x128>(v);   // row_ror:8
  v = dpp_add<0x124>(v);   // row_ror:4
  v = dpp_add<0x122>(v);   // row_ror:2
  v = dpp_add<0x121>(v);   // row_ror:1
  return v;
}
template <int CTRL>
__device__ __forceinline__ unsigned long long dpp_min_u64(unsigned long long k) {
  int lo = __builtin_amdgcn_update_dpp(0, (int)(unsigned)k, CTRL, 0xF, 0xF, false);
  int hi = __builtin_amdgcn_update_dpp(0, (int)(unsigned)(k >> 32), CTRL, 0xF, 0xF, false);
  unsigned long long o = ((unsigned long long)(unsigned)hi << 32) | (unsigned)lo;
  return o < k ? o : k;
}
__device__ __forceinline__ unsigned long long rmin16_u64(unsigned long long k) {
  k = dpp_min_u64<0x128>(k);
  k = dpp_min_u64<0x124>(k);
  k = dpp_min_u64<0x122>(k);
  k = dpp_min_u64<0x121>(k);
  return k;
}

__device__ __forceinline__ int cellco(float v) {
  int c = (int)(v * 10.0f);
  return min(max(c, 0), GRID - 1);
}

// D-layout f32 (x0: chans 0-31 rows, x1: chans 32-63) -> B-fragments for next layer.
__device__ __forceinline__ void buildB(const f32x16& x0, const f32x16& x1, int h, Frag Bf[4]) {
  unsigned Z[8][2];
  #pragma unroll
  for (int q = 0; q < 4; ++q) {
    Z[q][0]     = pk2(x0[4*q+0], x0[4*q+1]);
    Z[q][1]     = pk2(x0[4*q+2], x0[4*q+3]);
    Z[4+q][0]   = pk2(x1[4*q+0], x1[4*q+1]);
    Z[4+q][1]   = pk2(x1[4*q+2], x1[4*q+3]);
  }
  unsigned S[8][2];
  #pragma unroll
  for (int q = 0; q < 8; ++q) {
    S[q][0] = (unsigned)__shfl_xor((int)Z[q][0], 32);
    S[q][1] = (unsigned)__shfl_xor((int)Z[q][1], 32);
  }
  #pragma unroll
  for (int t = 0; t < 4; ++t) {
    int qq = (t >> 1) * 4 + 2 * (t & 1);
    Bf[t].u[0] = h ? S[qq+1][0] : Z[qq][0];
    Bf[t].u[1] = h ? S[qq+1][1] : Z[qq][1];
    Bf[t].u[2] = h ? Z[qq+1][0] : S[qq][0];
    Bf[t].u[3] = h ? Z[qq+1][1] : S[qq][1];
  }
}

__device__ __forceinline__ f32x16 biasAct(f32x16 d, const float4* bp, int mt, int h) {
  f32x16 r;
  #pragma unroll
  for (int q = 0; q < 4; ++q) {
    float4 bb = bp[h * 8 + mt * 4 + q];
    r[4*q+0] = lrelu(d[4*q+0] + bb.x);
    r[4*q+1] = lrelu(d[4*q+1] + bb.y);
    r[4*q+2] = lrelu(d[4*q+2] + bb.z);
    r[4*q+3] = lrelu(d[4*q+3] + bb.w);
  }
  return r;
}

// ---------------- prep: pack A-fragments (bf16, BN scale folded; Wg2 also folds RSQN) ----------------
struct PrepArgs {
  const float* W[9];       // W1,Wq,Wk,Wv,Wd2,Wg1,Wg2,W2,Wd1
  const float* scale[9];
  const float* bias[5];    // b1,bd2,bg1,bg2,b2
  const float* bd1;
};

__global__ __launch_bounds__(256) void prep_kernel(PrepArgs a, unsigned short* AF, float* biasAll) {
  int mi = blockIdx.x;
  int tid = threadIdx.x;
  if (mi < 8) {
    int off = (mi == 7) ? 29696 : mi * 4096;
    const float* W = a.W[mi];
    const float* G = a.scale[mi];
    unsigned short* dst = AF + off;
    for (int e = tid; e < 4096; e += 256) {
      int i = e & 7, lane = (e >> 3) & 63, t = (e >> 9) & 3, mt = e >> 11;
      int row = 32 * mt + (lane & 31);
      int k = 16 * t + 8 * (lane >> 5) + i;
      float v = W[row * 64 + k];
      if (G) v *= G[row] * BN_INV;
      if (mi == 6) v *= RSQN;                  // fold 1/sqrt(N) into Wg2
      __hip_bfloat16 hb = __float2bfloat16(v);
      __builtin_memcpy(&dst[e], &hb, 2);
    }
  } else {
    const float* W = a.W[8];
    const float* G = a.scale[8];
    for (int e = tid; e < 1024; e += 256) {
      int i = e & 7, lane = (e >> 3) & 63, mt = e >> 9;
      int row = 32 * mt + (lane & 31), h = lane >> 5;
      float v = 0.f;
      if (h == 0) {
        if (i < 3) v = W[row * 3 + i] * G[row] * BN_INV;
        else if (i == 3) v = a.bd1[row];
      }
      __hip_bfloat16 hb = __float2bfloat16(v);
      __builtin_memcpy(&AF[28672 + e], &hb, 2);
    }
    for (int e = tid; e < 320; e += 256) {
      int ai = e >> 6, idx = e & 63;
      int h = idx >> 5, mt = (idx >> 4) & 1, q = (idx >> 2) & 3, j = idx & 3;
      float bv = a.bias[ai][32 * mt + 8 * q + 4 * h + j];
      if (ai == 3) bv *= RSQN;                 // fold 1/sqrt(N) into bg2
      biasAll[e] = bv;
    }
  }
}

// ---------------- pos4 + cell id + histogram ----------------
__global__ __launch_bounds__(256) void pos4cid_kernel(
    const float* __restrict__ pos, float* __restrict__ pos4,
    int* __restrict__ cid16, int* __restrict__ cellCount)
{
  int i = blockIdx.x * 256 + threadIdx.x;
  int b = i >> 13;
  int n = i & (N - 1);
  const float* pb = pos + (size_t)b * 3 * N;
  float x = pb[n], y = pb[N + n], z = pb[2 * N + n];
  float4 v = {x, y, z, x * x + y * y + z * z};
  *reinterpret_cast<float4*>(pos4 + (size_t)i * 4) = v;
  int cid = (cellco(z) * GRID + cellco(y)) * GRID + cellco(x);
  cid16[i] = cid;
  atomicAdd(&cellCount[b * GC + cid], 1);
}

// ---------------- scan: exclusive prefix over 2048 cell counts (single block) ----------------
__global__ __launch_bounds__(1024) void scan_kernel(
    const int* __restrict__ cnt, int* __restrict__ cellStart)
{
  __shared__ int s[2][2048];
  int t = threadIdx.x;
  s[0][t] = cnt[t];
  s[0][t + 1024] = cnt[t + 1024];
  __syncthreads();
  int src = 0;
  for (int off = 1; off < 2048; off <<= 1) {
    int dst = src ^ 1;
    for (int i = t; i < 2048; i += 1024) {
      int v = s[src][i];
      if (i >= off) v += s[src][i - off];
      s[dst][i] = v;
    }
    __syncthreads();
    src ^= 1;
  }
  cellStart[t] = (t == 0) ? 0 : s[src][t - 1];
  cellStart[t + 1024] = s[src][t + 1023];
}

// ---------------- scatter: counting-sort points by cell (+ inverse map orig->sorted) ----------------
__global__ __launch_bounds__(256) void scatter_kernel(
    const float* __restrict__ pos4, const int* __restrict__ cid16,
    const int* __restrict__ cellStart, int* __restrict__ cellOfs,
    float4* __restrict__ pos4s, int* __restrict__ sid, int* __restrict__ inv)
{
  int i = blockIdx.x * 256 + threadIdx.x;
  int b = i >> 13;
  int cg = b * GC + cid16[i];
  int dst = cellStart[cg] + atomicAdd(&cellOfs[cg], 1);
  pos4s[dst] = *reinterpret_cast<const float4*>(pos4 + (size_t)i * 4);
  sid[dst] = i & (N - 1);
  inv[i] = dst;                                // global sorted slot of orig point
}

// ---------------- knn + qkv fat kernel: blocks [0,1024) = knn, [1024,1408) = qkv ----------------
// knn: 16-lane group per query; INCREMENTAL shell scan (dk persists across radii; radius r
// scans only window(r)\window(r-1)); COUNT-based certificate (16 compares + rsum16; exact
// since a truncated lane alone contributes 16); extraction runs exactly ONCE per query.
// qkv: MFMA path; backfills SIMDs as knn's long-pole waves drain.
__global__ __launch_bounds__(256) void knnqkv_kernel(
    const float4* __restrict__ pos4s, const int* __restrict__ sid,
    const int* __restrict__ cellStart, int* __restrict__ knn_s,
    const float* __restrict__ feats, const int4* __restrict__ AF,
    const float* __restrict__ b1p, const int* __restrict__ inv,
    uint2* __restrict__ qT, uint2* __restrict__ kT, uint2* __restrict__ vT)
{
  __shared__ int4 sA[1024];

  if (blockIdx.x < KNN_BLOCKS) {
    // ---------------- knn path ----------------
    constexpr unsigned long long SENT = ~0ULL;
    int lq = threadIdx.x & 15;
    int wid = (blockIdx.x * 256 + threadIdx.x) >> 4;   // query = global sorted slot
    int b = wid >> 13;
    float4 q = pos4s[wid];
    int cx = cellco(q.x), cy = cellco(q.y), cz = cellco(q.z);
    const int cbase = b * GC;

    int nb = (int)(cx == 0 || cx == GRID - 1) + (int)(cy == 0 || cy == GRID - 1)
           + (int)(cz == 0 || cz == GRID - 1);
    int r0 = (nb >= 2) ? 2 : 1;                        // group-uniform

    unsigned long long dk[16];
    #pragma unroll
    for (int j = 0; j < 16; ++j) dk[j] = SENT;

    auto scanSeg = [&](int i0, int i1) {
      #pragma unroll 1
      for (int i = i0 + lq; i < i1; i += 16) {
        float4 cp = pos4s[i];
        float inn = q.x * cp.x + q.y * cp.y + q.z * cp.z;
        float dist = fmaxf(fmaf(-2.f, inn, q.w + cp.w), 0.f);
        unsigned long long key =
            ((unsigned long long)__float_as_uint(dist) << 26) |
            ((unsigned long long)(unsigned)sid[i] << 13) |
            (unsigned long long)(unsigned)(i & (N - 1));
        if (key < dk[15]) {
          bool bj = true;
          #pragma unroll
          for (int j = 15; j >= 1; --j) {
            bool bjm1 = key < dk[j - 1];
            dk[j] = bj ? (bjm1 ? dk[j - 1] : key) : dk[j];
            bj = bjm1;
          }
          if (bj) dk[0] = key;
        }
      }
    };

    bool done = false, first = true;
    #pragma unroll 1
    for (int r = 1; r < GRID; ++r) {
      if (r >= r0 && !done) {
        int x0 = max(cx - r, 0), x1 = min(cx + r, GRID - 1);
        int y0 = max(cy - r, 0), y1 = min(cy + r, GRID - 1);
        int z0 = max(cz - r, 0), z1 = min(cz + r, GRID - 1);
        int rin = first ? -1 : r - 1;                  // inner (already scanned) window
        int xi0 = max(cx - rin, 0), xi1 = min(cx + rin, GRID - 1);
        int yi0 = max(cy - rin, 0), yi1 = min(cy + rin, GRID - 1);
        int zi0 = max(cz - rin, 0), zi1 = min(cz + rin, GRID - 1);
        #pragma unroll 1
        for (int zz = z0; zz <= z1; ++zz) {
          bool zout = (zz < zi0) || (zz > zi1);
          #pragma unroll 1
          for (int yy = y0; yy <= y1; ++yy) {
            bool rowfull = zout || (yy < yi0) || (yy > yi1);
            int rowc = cbase + (zz * GRID + yy) * GRID;
            if (rowfull) {
              scanSeg(cellStart[rowc + x0], cellStart[rowc + x1 + 1]);
            } else {
              if (x0 < xi0) scanSeg(cellStart[rowc + x0], cellStart[rowc + xi0]);
              if (xi1 < x1) scanSeg(cellStart[rowc + xi1 + 1], cellStart[rowc + x1 + 1]);
            }
          }
        }
        first = false;

        // count-based certificate: #candidates <= mg^2 over scanned window >= 16 ?
        float mg = 3.4e38f;
        if (cx - r > 0)        mg = fminf(mg, q.x - (cx - r) * H);
        if (cx + r < GRID - 1) mg = fminf(mg, (cx + r + 1) * H - q.x);
        if (cy - r > 0)        mg = fminf(mg, q.y - (cy - r) * H);
        if (cy + r < GRID - 1) mg = fminf(mg, (cy + r + 1) * H - q.y);
        if (cz - r > 0)        mg = fminf(mg, q.z - (cz - r) * H);
        if (cz + r < GRID - 1) mg = fminf(mg, (cz + r + 1) * H - q.z);
        float thr = mg * mg * 0.999f;                  // inf ok: all keys count
        unsigned long long tk = ((unsigned long long)__float_as_uint(thr)) << 26;
        float c = 0.f;
        #pragma unroll
        for (int j = 0; j < 16; ++j) c += (dk[j] < tk) ? 1.f : 0.f;
        c = rsum16(c);
        done = (c > 15.5f);                            // group-uniform
      }
      if (__all(done)) break;
    }

    // single extraction: group top-16 via DPP u64 min; round-e winner kept by lane e
    int myout = 0;
    #pragma unroll 1
    for (int e = 0; e < 16; ++e) {
      unsigned long long m = rmin16_u64(dk[0]);
      if (dk[0] == m) {                          // unique winner (keys embed unique ids)
        #pragma unroll
        for (int j = 0; j < 15; ++j) dk[j] = dk[j + 1];
        dk[15] = SENT;
      }
      if (lq == e) myout = (int)(m & 0x1FFFULL);
    }
    knn_s[(size_t)wid * 16 + lq] = myout;        // one coalesced store per group
    return;
  }

  // ---------------- qkv path ----------------
  int qb = blockIdx.x - KNN_BLOCKS;
  int my = qb >> 7;                              // output matrix 0..2
  int gx = qb & 127;
  for (int i = threadIdx.x; i < 512; i += 256) {
    sA[i] = AF[i];
    sA[512 + i] = AF[512 * (1 + my) + i];
  }
  __syncthreads();
  int lane = threadIdx.x & 63, w = threadIdx.x >> 6;
  int gw = gx * 4 + w;
  int col = lane & 31, h = lane >> 5;
  int nb_ = gw * 32;
  int b = nb_ >> 13;
  int n = (nb_ & (N - 1)) + col;
  size_t gpt = (size_t)b * N + n;
  int sv = inv[gpt];                             // sorted slot (coalesced read)
  const float* fb = feats + (size_t)b * D * N + n;

  Frag Bf[4];
  #pragma unroll
  for (int t = 0; t < 4; ++t) {
    int c0 = 16 * t + 8 * h;
    float f[8];
    #pragma unroll
    for (int i = 0; i < 8; ++i) f[i] = fb[(size_t)(c0 + i) * N];
    #pragma unroll
    for (int d_ = 0; d_ < 4; ++d_) Bf[t].u[d_] = pk2(f[2*d_], f[2*d_+1]);
  }
  f32x16 acc0 = {}, acc1 = {};
  #pragma unroll
  for (int t = 0; t < 4; ++t) {
    acc0 = MF(sA[t * 64 + lane], Bf[t], acc0);
    acc1 = MF(sA[(4 + t) * 64 + lane], Bf[t], acc1);
  }
  const float4* bp = (const float4*)b1p;
  f32x16 x0 = biasAct(acc0, bp, 0, h);
  f32x16 x1 = biasAct(acc1, bp, 1, h);
  Frag Bx[4];
  buildB(x0, x1, h, Bx);

  uint2* op = (my == 0) ? qT : (my == 1) ? kT : vT;
  f32x16 a0 = {}, a1 = {};
  #pragma unroll
  for (int t = 0; t < 4; ++t) {
    a0 = MF(sA[512 + t * 64 + lane], Bx[t], a0);
    a1 = MF(sA[512 + (4 + t) * 64 + lane], Bx[t], a1);
  }
  #pragma unroll
  for (int q = 0; q < 4; ++q) {
    uint2 v0, v1;
    v0.x = pk2(a0[4*q+0], a0[4*q+1]); v0.y = pk2(a0[4*q+2], a0[4*q+3]);
    v1.x = pk2(a1[4*q+0], a1[4*q+1]); v1.y = pk2(a1[4*q+2], a1[4*q+3]);
    op[(size_t)sv * 16 + 2 * q + h] = v0;        // scatter write to sorted slot
    op[(size_t)sv * 16 + 8 + 2 * q + h] = v1;
  }
}

// ---------------- fused (MFMA): LDS weights; inline sorted-space gathers; DPP softmax ----------------
__global__ __launch_bounds__(256) void fused_kernel(
    const float4* __restrict__ pos4s, const int* __restrict__ sid,
    const int* __restrict__ knn_s,
    const uint2* __restrict__ qT, const uint2* __restrict__ kT, const uint2* __restrict__ vT,
    const int4* __restrict__ AF,      // [Wd2 | Wg1 | Wg2 | Wd1]
    const float* __restrict__ biases, // bd2p | bg1p | bg2p(RSQN-folded)
    uint2* __restrict__ res_ws)       // bf16-packed res, orig order, B-frag pair layout
{
  int lane = threadIdx.x & 63, w = threadIdx.x >> 6;
  int gw = blockIdx.x * 4 + w;
  int col = lane & 31, h = lane >> 5;
  int p = col >> 4, kk = col & 15;
  int sbase = gw * 2;
  int b = sbase >> 13;
  int s = sbase + p;                            // global sorted slot of own point

  // point-level loads issued before LDS stage (hide under stage+barrier)
  int m_loc = knn_s[(size_t)s * 16 + kk];       // sorted-local neighbor idx (coalesced)
  int orig = sid[s];
  float4 P = pos4s[s];

  __shared__ int4 sA[1664];
  for (int i = threadIdx.x; i < 1664; i += 256) sA[i] = AF[i];
  __syncthreads();
  const float4* bpd2 = (const float4*)(biases);
  const float4* bpg1 = (const float4*)(biases + 64);
  const float4* bpg2 = (const float4*)(biases + 128);

  size_t ms = (size_t)b * N + m_loc;            // global sorted neighbor slot
  float4 Q = pos4s[ms];
  float rx = P.x - Q.x, ry = P.y - Q.y, rz = P.z - Q.z;

  // L0: pe = lrelu(s*Wd1@rel + bd1)   (bias via B k=3 column)
  Frag B0;
  B0.u[0] = h ? 0u : pk2(rx, ry);
  B0.u[1] = h ? 0u : pk2(rz, 1.0f);
  B0.u[2] = 0u; B0.u[3] = 0u;
  f32x16 acc0 = {}, acc1 = {};
  acc0 = MF(sA[1536 + lane], B0, acc0);
  acc1 = MF(sA[1600 + lane], B0, acc1);
  f32x16 pe0, pe1;
  #pragma unroll
  for (int i = 0; i < 16; ++i) { pe0[i] = lrelu(acc0[i]); pe1[i] = lrelu(acc1[i]); }
  Frag Bp[4];
  buildB(pe0, pe1, h, Bp);

  // L1: pos_enc = lrelu(s*Wd2@pe + bd2)
  acc0 = (f32x16){}; acc1 = (f32x16){};
  #pragma unroll
  for (int t = 0; t < 4; ++t) {
    acc0 = MF(sA[t * 64 + lane], Bp[t], acc0);
    acc1 = MF(sA[(4 + t) * 64 + lane], Bp[t], acc1);
  }
  f32x16 pn0 = biasAct(acc0, bpd2, 0, h);
  f32x16 pn1 = biasAct(acc1, bpd2, 1, h);

  unsigned pep[8][2];
  #pragma unroll
  for (int q = 0; q < 4; ++q) {
    pep[q][0]   = pk2(pn0[4*q+0], pn0[4*q+1]);
    pep[q][1]   = pk2(pn0[4*q+2], pn0[4*q+3]);
    pep[4+q][0] = pk2(pn1[4*q+0], pn1[4*q+1]);
    pep[4+q][1] = pk2(pn1[4*q+2], pn1[4*q+3]);
  }

  // a0 = q[n] - k[m] + pos_enc   (gathers read inline, sorted space)
  f32x16 av0, av1;
  #pragma unroll
  for (int mt = 0; mt < 2; ++mt) {
    f32x16& dst = mt ? av1 : av0;
    const f32x16& pn = mt ? pn1 : pn0;
    #pragma unroll
    for (int q = 0; q < 4; ++q) {
      uint2 qq_ = qT[(size_t)s * 16 + 8 * mt + 2 * q + h];
      uint2 kq_ = kT[ms * 16 + 8 * mt + 2 * q + h];
      dst[4*q+0] = pn[4*q+0] + blo(qq_.x) - blo(kq_.x);
      dst[4*q+1] = pn[4*q+1] + bhi(qq_.x) - bhi(kq_.x);
      dst[4*q+2] = pn[4*q+2] + blo(qq_.y) - blo(kq_.y);
      dst[4*q+3] = pn[4*q+3] + bhi(qq_.y) - bhi(kq_.y);
    }
  }
  buildB(av0, av1, h, Bp);

  // L2: a1 = lrelu(s*Wg1@a0 + bg1)
  acc0 = (f32x16){}; acc1 = (f32x16){};
  #pragma unroll
  for (int t = 0; t < 4; ++t) {
    acc0 = MF(sA[512 + t * 64 + lane], Bp[t], acc0);
    acc1 = MF(sA[512 + (4 + t) * 64 + lane], Bp[t], acc1);
  }
  f32x16 a10 = biasAct(acc0, bpg1, 0, h);
  f32x16 a11 = biasAct(acc1, bpg1, 1, h);
  buildB(a10, a11, h, Bp);

  // L3: a2 = lrelu(s'*Wg2@a1 + bg2')   (RSQN pre-folded)
  acc0 = (f32x16){}; acc1 = (f32x16){};
  #pragma unroll
  for (int t = 0; t < 4; ++t) {
    acc0 = MF(sA[1024 + t * 64 + lane], Bp[t], acc0);
    acc1 = MF(sA[1024 + (4 + t) * 64 + lane], Bp[t], acc1);
  }
  f32x16 at0 = biasAct(acc0, bpg2, 0, h);
  f32x16 at1 = biasAct(acc1, bpg2, 1, h);

  // softmax over kk (DPP rotate-reduce) + weighted sum of vpe = v + pos_enc (v read inline)
  uint2* rp = res_ws + ((size_t)b * N + orig) * 16;
  #pragma unroll
  for (int mt = 0; mt < 2; ++mt) {
    const f32x16& at = mt ? at1 : at0;
    f32x16 ev, nm;
    #pragma unroll
    for (int q = 0; q < 4; ++q) {
      uint2 vq_ = vT[ms * 16 + 8 * mt + 2 * q + h];
      unsigned pp0 = pep[mt * 4 + q][0], pp1 = pep[mt * 4 + q][1];
      float vp0 = blo(vq_.x) + blo(pp0);
      float vp1 = bhi(vq_.x) + bhi(pp0);
      float vp2 = blo(vq_.y) + blo(pp1);
      float vp3 = bhi(vq_.y) + bhi(pp1);
      ev[4*q+0] = __expf(at[4*q+0]); nm[4*q+0] = ev[4*q+0] * vp0;
      ev[4*q+1] = __expf(at[4*q+1]); nm[4*q+1] = ev[4*q+1] * vp1;
      ev[4*q+2] = __expf(at[4*q+2]); nm[4*q+2] = ev[4*q+2] * vp2;
      ev[4*q+3] = __expf(at[4*q+3]); nm[4*q+3] = ev[4*q+3] * vp3;
    }
    #pragma unroll
    for (int i = 0; i < 16; ++i) {
      ev[i] = rsum16(ev[i]);
      nm[i] = rsum16(nm[i]);
    }
    if (kk == 0) {
      #pragma unroll
      for (int q = 0; q < 4; ++q) {
        uint2 rr;
        rr.x = pk2(nm[4*q+0] / ev[4*q+0], nm[4*q+1] / ev[4*q+1]);
        rr.y = pk2(nm[4*q+2] / ev[4*q+2], nm[4*q+3] / ev[4*q+3]);
        rp[8 * mt + 2 * q + h] = rr;
      }
    }
  }
}

// ---------------- final (MFMA): out = lrelu(bn(W2@res)) + feats ----------------
__global__ __launch_bounds__(256) void final_kernel(
    const uint2* __restrict__ res_ws, const int4* __restrict__ AF,
    const float* __restrict__ b2p, const float* __restrict__ feats,
    float* __restrict__ out)
{
  __shared__ int4 sA[512];
  for (int i = threadIdx.x; i < 512; i += 256) sA[i] = AF[i];
  __syncthreads();
  int lane = threadIdx.x & 63, w = threadIdx.x >> 6;
  int gw = blockIdx.x * 4 + w;
  int col = lane & 31, h = lane >> 5;
  int nb = gw * 32;
  int b = nb >> 13;
  int n = (nb & (N - 1)) + col;
  size_t g = (size_t)b * N + n;
  const int4* rp = (const int4*)(res_ws + (size_t)g * 16);
  Frag Br[4];
  #pragma unroll
  for (int t = 0; t < 4; ++t) Br[t].i4 = rp[2 * t + h];
  f32x16 a0 = {}, a1 = {};
  #pragma unroll
  for (int t = 0; t < 4; ++t) {
    a0 = MF(sA[t * 64 + lane], Br[t], a0);
    a1 = MF(sA[(4 + t) * 64 + lane], Br[t], a1);
  }
  const float4* bp = (const float4*)b2p;
  f32x16 o0 = biasAct(a0, bp, 0, h);
  f32x16 o1 = biasAct(a1, bp, 1, h);
  const float* fb = feats + (size_t)b * D * N;
  float* ob = out + (size_t)b * D * N;
  #pragma unroll
  for (int mt = 0; mt < 2; ++mt) {
    const f32x16& oo = mt ? o1 : o0;
    #pragma unroll
    for (int q = 0; q < 4; ++q) {
      #pragma unroll
      for (int j = 0; j < 4; ++j) {
        int chan = 32 * mt + 8 * q + 4 * h + j;
        ob[(size_t)chan * N + n] = oo[4*q+j] + fb[(size_t)chan * N + n];
      }
    }
  }
}

} // namespace

extern "C" void kernel_launch(void* const* d_in, const int* in_sizes, int n_in,
                              void* d_out, int out_size, void* d_ws, size_t ws_size,
                              hipStream_t stream) {
  const float* feats = (const float*)d_in[0];
  const float* pos   = (const float*)d_in[1];
  const float* W1  = (const float*)d_in[3];
  const float* g1  = (const float*)d_in[4];
  const float* b1  = (const float*)d_in[5];
  const float* Wq  = (const float*)d_in[6];
  const float* Wk  = (const float*)d_in[7];
  const float* Wv  = (const float*)d_in[8];
  const float* Wd1 = (const float*)d_in[9];
  const float* gd1 = (const float*)d_in[10];
  const float* bd1 = (const float*)d_in[11];
  const float* Wd2 = (const float*)d_in[12];
  const float* gd2 = (const float*)d_in[13];
  const float* bd2 = (const float*)d_in[14];
  const float* Wg1 = (const float*)d_in[15];
  const float* gg1 = (const float*)d_in[16];
  const float* bg1 = (const float*)d_in[17];
  const float* Wg2 = (const float*)d_in[18];
  const float* gg2 = (const float*)d_in[19];
  const float* bg2 = (const float*)d_in[20];
  const float* W2  = (const float*)d_in[21];
  const float* g2  = (const float*)d_in[22];
  const float* b2  = (const float*)d_in[23];

  uint8_t* wsb = (uint8_t*)d_ws;
  unsigned short* AF = (unsigned short*)wsb;               // bf16 A-frags (73728 B reserved)
  float* biasAll = (float*)(wsb + 73728);                  // 320 floats
  float* pos4    = (float*)(wsb + 75008);                  // 65536 floats (256 KB)
  uint2* qTb     = (uint2*)(wsb + 337152);                 // 2 MB (sorted-slot layout)
  uint2* kTb     = (uint2*)(wsb + 2434304);                // 2 MB
  uint2* vTb     = (uint2*)(wsb + 4531456);                // 2 MB
  uint2* res_ws  = (uint2*)(wsb + 6628608);                // 2 MB (bf16-packed; 4 MB reserved)
  int*   cid16     = (int*)(wsb + 10822912);               // 64 KB
  int*   cellCount = (int*)(wsb + 10888448);               // 8 KB (2048)
  int*   cellStart = (int*)(wsb + 10896640);               // 8 KB (2048+1)
  int*   cellOfs   = (int*)(wsb + 10904832);               // 8 KB (2048)
  float4* pos4s    = (float4*)(wsb + 10913024);            // 256 KB
  int*   sid       = (int*)(wsb + 11175168);               // 64 KB
  int*   knn_s     = (int*)(wsb + 11240704);               // 1 MB (16384*16*4)
  int*   inv       = (int*)(wsb + 12289280);               // 64 KB

  PrepArgs pa;
  pa.W[0] = W1;  pa.W[1] = Wq;  pa.W[2] = Wk;  pa.W[3] = Wv;
  pa.W[4] = Wd2; pa.W[5] = Wg1; pa.W[6] = Wg2; pa.W[7] = W2; pa.W[8] = Wd1;
  pa.scale[0] = g1;  pa.scale[1] = nullptr; pa.scale[2] = nullptr; pa.scale[3] = nullptr;
  pa.scale[4] = gd2; pa.scale[5] = gg1;     pa.scale[6] = gg2;     pa.scale[7] = g2; pa.scale[8] = gd1;
  pa.bias[0] = b1; pa.bias[1] = bd2; pa.bias[2] = bg1; pa.bias[3] = bg2; pa.bias[4] = b2;
  pa.bd1 = bd1;

  hipMemsetAsync(cellCount, 0, 2048 * sizeof(int), stream);
  hipMemsetAsync(cellOfs, 0, 2048 * sizeof(int), stream);
  hipLaunchKernelGGL(prep_kernel, dim3(9), dim3(256), 0, stream, pa, AF, biasAll);
  hipLaunchKernelGGL(pos4cid_kernel, dim3(B * N / 256), dim3(256), 0, stream,
                     pos, pos4, cid16, cellCount);
  hipLaunchKernelGGL(scan_kernel, dim3(1), dim3(1024), 0, stream, cellCount, cellStart);
  hipLaunchKernelGGL(scatter_kernel, dim3(B * N / 256), dim3(256), 0, stream,
                     pos4, cid16, cellStart, cellOfs, pos4s, sid, inv);
  hipLaunchKernelGGL(knnqkv_kernel, dim3(KNN_BLOCKS + 384), dim3(256), 0, stream,
                     pos4s, sid, cellStart, knn_s,
                     feats, (const int4*)wsb, biasAll, inv, qTb, kTb, vTb);
  hipLaunchKernelGGL(fused_kernel, dim3(B * N / 8), dim3(256), 0, stream,
                     pos4s, sid, knn_s, qTb, kTb, vTb,
                     (const int4*)(wsb + 32768), biasAll + 64, res_ws);
  hipLaunchKernelGGL(final_kernel, dim3(128), dim3(256), 0, stream,
                     res_ws, (const int4*)(wsb + 59392), biasAll + 256, feats, (float*)d_out);
}